// Round 1
// baseline (25487.515 us; speedup 1.0000x reference)
//
#include <hip/hip_runtime.h>
#include <stdint.h>

#define HH 256
#define SS 2048
#define BB 256
#define DD 64
#define NG 16   // batch groups (16 rows each)
#define NW 16   // col waves per group (16 h-cols each)

typedef __attribute__((ext_vector_type(8))) short bh8;
typedef __attribute__((ext_vector_type(4))) float fx4;
typedef __attribute__((ext_vector_type(4))) float f4v;

__device__ __forceinline__ short f2bf(float f) {
  uint32_t u = __builtin_bit_cast(uint32_t, f);
  u += 0x7FFFu + ((u >> 16) & 1u);
  return (short)(u >> 16);
}
__device__ __forceinline__ float bf2f(short s) {
  uint32_t u = ((uint32_t)(uint16_t)s) << 16;
  return __builtin_bit_cast(float, u);
}
__device__ __forceinline__ float sigm_(float x) {
  x = fminf(fmaxf(x, -30.f), 30.f);
  return 1.0f / (1.0f + __expf(-x));
}
__device__ __forceinline__ float tanh_(float x) {
  x = fminf(fmaxf(x, -15.f), 15.f);
  float e = __expf(2.0f * x);
  return (e - 1.0f) / (e + 1.0f);
}
__device__ __forceinline__ fx4 mfma16(bh8 a, bh8 b, fx4 c) {
  return __builtin_amdgcn_mfma_f32_16x16x32_bf16(a, b, c, 0, 0, 0);
}
__device__ __forceinline__ bh8 cvt8(f4v a, f4v b) {
  bh8 r;
  r[0]=f2bf(a[0]); r[1]=f2bf(a[1]); r[2]=f2bf(a[2]); r[3]=f2bf(a[3]);
  r[4]=f2bf(b[0]); r[5]=f2bf(b[1]); r[6]=f2bf(b[2]); r[7]=f2bf(b[3]);
  return r;
}

// ws layout (bytes):
//   [g*64]           : cnt0[g]  (one 64B line per group)
//   [2048 + g*64]    : cnt1[g]
//   [8192 ...]       : ys frags  [S][NG][8 frag][64 lane][8] bf16  = 256 MB
//   [8192 + 2^28 ..] : ring frags [2][NG][8][64][8] bf16           = 256 KB
#define YS_OFF   8192
#define RING_OFF (8192 + 268435456ull)
#define WS_NEED  (RING_OFF + 262144ull)

__global__ __launch_bounds__(64, 1) void gru_rec(
    const float* __restrict__ x,
    const float* __restrict__ Wih0, const float* __restrict__ Whh0,
    const float* __restrict__ bih0, const float* __restrict__ bhh0,
    const float* __restrict__ Wih1, const float* __restrict__ Whh1,
    const float* __restrict__ bih1, const float* __restrict__ bhh1,
    uint8_t* __restrict__ ws)
{
  const int l      = threadIdx.x;   // 0..63
  const int lane15 = l & 15;
  const int lgrp   = l >> 4;        // 0..3
  const int bid    = blockIdx.x;
  const int layer  = bid >> 8;
  const int r8     = bid & 255;
  const int g      = r8 & 15;       // group (batch tile)
  const int cp     = r8 >> 4;       // col wave 0..15
  const int jg     = cp * 16 + lane15;  // global h column
  const int fidx   = cp >> 1;       // frag index 0..7
  const int half   = cp & 1;        // frag half

  uint32_t* cnt0 = (uint32_t*)(ws + (size_t)g * 64);
  uint32_t* cnt1 = (uint32_t*)(ws + 2048 + (size_t)g * 64);
  short* ys   = (short*)(ws + YS_OFF);
  short* ring = (short*)(ws + RING_OFF);

  __shared__ short pub[256];  // 512B wave-local transpose buffer

  const float* Wih = layer ? Wih1 : Wih0;
  const float* Whh = layer ? Whh1 : Whh0;
  const float* bih = layer ? bih1 : bih0;
  const float* bhh = layer ? bhh1 : bhh0;

  const float biR = bih[jg],      biZ = bih[HH + jg],  biN = bih[2*HH + jg];
  const float bhR = bhh[jg],      bhZ = bhh[HH + jg],  bhN = bhh[2*HH + jg];

  // ---- W_hh B-fragments into registers (both layers: 3 gates x 8 kfrags)
  bh8 whhF[3][8];
#pragma unroll
  for (int gi = 0; gi < 3; ++gi) {
    int grow = gi * HH + jg;
#pragma unroll
    for (int kf = 0; kf < 8; ++kf) {
      const float* p = Whh + (size_t)grow * HH + kf * 32 + lgrp * 8;
      whhF[gi][kf] = cvt8(*(const f4v*)p, *(const f4v*)(p + 4));
    }
  }

  float hp[4] = {0.f, 0.f, 0.f, 0.f};

  if (layer == 0) {
    // ---- W_ih0 frags (K=64 -> 2 kfrags)
    bh8 wihF[3][2];
#pragma unroll
    for (int gi = 0; gi < 3; ++gi) {
      int grow = gi * HH + jg;
#pragma unroll
      for (int kf = 0; kf < 2; ++kf) {
        const float* p = Wih + (size_t)grow * DD + kf * 32 + lgrp * 8;
        wihF[gi][kf] = cvt8(*(const f4v*)p, *(const f4v*)(p + 4));
      }
    }
    // preload x[0]
    const float* xp0 = x + ((size_t)0 * BB + g * 16 + lane15) * DD + lgrp * 8;
    f4v px0 = *(const f4v*)xp0,        px1 = *(const f4v*)(xp0 + 4);
    f4v px2 = *(const f4v*)(xp0 + 32), px3 = *(const f4v*)(xp0 + 36);

    uint32_t seen = 0;
    for (int t = 0; t < SS; ++t) {
      fx4 accR = {0,0,0,0}, accZ = {0,0,0,0}, accXN = {0,0,0,0}, accHN = {0,0,0,0};
      bh8 xf0 = cvt8(px0, px1), xf1 = cvt8(px2, px3);
      if (t + 1 < SS) {  // prefetch next x tile
        const float* xp = x + ((size_t)(t+1) * BB + g * 16 + lane15) * DD + lgrp * 8;
        px0 = *(const f4v*)xp;        px1 = *(const f4v*)(xp + 4);
        px2 = *(const f4v*)(xp + 32); px3 = *(const f4v*)(xp + 36);
      }
      accR  = mfma16(xf0, wihF[0][0], accR);  accR  = mfma16(xf1, wihF[0][1], accR);
      accZ  = mfma16(xf0, wihF[1][0], accZ);  accZ  = mfma16(xf1, wihF[1][1], accZ);
      accXN = mfma16(xf0, wihF[2][0], accXN); accXN = mfma16(xf1, wihF[2][1], accXN);

      if (t > 0) {
        if (l == 0) {
          uint32_t need = 16u * (uint32_t)t;
          while (seen < need) {
            seen = __hip_atomic_fetch_add(cnt0, 0u, __ATOMIC_RELAXED, __HIP_MEMORY_SCOPE_AGENT);
            if (seen < need) __builtin_amdgcn_s_sleep(1);
          }
        }
        __builtin_amdgcn_fence(__ATOMIC_ACQUIRE, "agent");
        const bh8* asrc = (const bh8*)(ys + ((size_t)(t - 1) * NG + g) * 4096);
        bh8 af[8];
#pragma unroll
        for (int kf = 0; kf < 8; ++kf) af[kf] = asrc[kf * 64 + l];
#pragma unroll
        for (int kf = 0; kf < 8; ++kf) {
          accR  = mfma16(af[kf], whhF[0][kf], accR);
          accZ  = mfma16(af[kf], whhF[1][kf], accZ);
          accHN = mfma16(af[kf], whhF[2][kf], accHN);
        }
      }
#pragma unroll
      for (int i = 0; i < 4; ++i) {
        float r = sigm_(accR[i] + biR + bhR);
        float z = sigm_(accZ[i] + biZ + bhZ);
        float n = tanh_(accXN[i] + biN + r * (accHN[i] + bhN));
        float h = (1.0f - z) * n + z * hp[i];
        short hb = f2bf(h);
        hp[i] = bf2f(hb);
        pub[(lgrp * 4 + i + ((lane15 >> 3) << 4)) * 8 + (lane15 & 7)] = hb;
      }
      __syncthreads();
      int2 v = *(const int2*)&pub[l * 4];
      short* dst = ys + (((size_t)t * NG + g) * 8 + fidx) * 512 + half * 256 + l * 4;
      *(int2*)dst = v;
      if (l == 0)
        __hip_atomic_fetch_add(cnt0, 1u, __ATOMIC_RELEASE, __HIP_MEMORY_SCOPE_AGENT);
      __syncthreads();
    }
  } else {
    // ---- layer 1: W_ih1 frags (K=256 -> 8 kfrags)
    bh8 wihF[3][8];
#pragma unroll
    for (int gi = 0; gi < 3; ++gi) {
      int grow = gi * HH + jg;
#pragma unroll
      for (int kf = 0; kf < 8; ++kf) {
        const float* p = Wih + (size_t)grow * HH + kf * 32 + lgrp * 8;
        wihF[gi][kf] = cvt8(*(const f4v*)p, *(const f4v*)(p + 4));
      }
    }
    uint32_t seen0 = 0, seen1 = 0;
    for (int t = 0; t < SS; ++t) {
      fx4 accR = {0,0,0,0}, accZ = {0,0,0,0}, accXN = {0,0,0,0}, accHN = {0,0,0,0};
      // wait for ys0[t]
      if (l == 0) {
        uint32_t need = 16u * (uint32_t)(t + 1);
        while (seen0 < need) {
          seen0 = __hip_atomic_fetch_add(cnt0, 0u, __ATOMIC_RELAXED, __HIP_MEMORY_SCOPE_AGENT);
          if (seen0 < need) __builtin_amdgcn_s_sleep(2);
        }
      }
      __builtin_amdgcn_fence(__ATOMIC_ACQUIRE, "agent");
      const bh8* xsrc = (const bh8*)(ys + ((size_t)t * NG + g) * 4096);
      bh8 xf[8];
#pragma unroll
      for (int kf = 0; kf < 8; ++kf) xf[kf] = xsrc[kf * 64 + l];
#pragma unroll
      for (int kf = 0; kf < 8; ++kf) {
        accR  = mfma16(xf[kf], wihF[0][kf], accR);
        accZ  = mfma16(xf[kf], wihF[1][kf], accZ);
        accXN = mfma16(xf[kf], wihF[2][kf], accXN);
      }
      if (t > 0) {
        if (l == 0) {
          uint32_t need = 16u * (uint32_t)t;
          while (seen1 < need) {
            seen1 = __hip_atomic_fetch_add(cnt1, 0u, __ATOMIC_RELAXED, __HIP_MEMORY_SCOPE_AGENT);
            if (seen1 < need) __builtin_amdgcn_s_sleep(1);
          }
        }
        __builtin_amdgcn_fence(__ATOMIC_ACQUIRE, "agent");
        const bh8* asrc = (const bh8*)(ring + ((size_t)((t - 1) & 1) * NG + g) * 4096);
        bh8 af[8];
#pragma unroll
        for (int kf = 0; kf < 8; ++kf) af[kf] = asrc[kf * 64 + l];
#pragma unroll
        for (int kf = 0; kf < 8; ++kf) {
          accR  = mfma16(af[kf], whhF[0][kf], accR);
          accZ  = mfma16(af[kf], whhF[1][kf], accZ);
          accHN = mfma16(af[kf], whhF[2][kf], accHN);
        }
      }
#pragma unroll
      for (int i = 0; i < 4; ++i) {
        float r = sigm_(accR[i] + biR + bhR);
        float z = sigm_(accZ[i] + biZ + bhZ);
        float n = tanh_(accXN[i] + biN + r * (accHN[i] + bhN));
        float h = (1.0f - z) * n + z * hp[i];
        short hb = f2bf(h);
        hp[i] = bf2f(hb);
        pub[(lgrp * 4 + i + ((lane15 >> 3) << 4)) * 8 + (lane15 & 7)] = hb;
      }
      __syncthreads();
      int2 v = *(const int2*)&pub[l * 4];
      short* dst = ring + (((size_t)(t & 1) * NG + g) * 8 + fidx) * 512 + half * 256 + l * 4;
      *(int2*)dst = v;
      if (l == 0)
        __hip_atomic_fetch_add(cnt1, 1u, __ATOMIC_RELEASE, __HIP_MEMORY_SCOPE_AGENT);
      __syncthreads();
    }
  }
}

__global__ __launch_bounds__(512) void gru_out(
    const uint8_t* __restrict__ ws,
    const float* __restrict__ Wout, const float* __restrict__ bout,
    float* __restrict__ out)
{
  const short* ys   = (const short*)(ws + YS_OFF);
  const short* ring = (const short*)(ws + RING_OFF);
  int bid = blockIdx.x;        // 0..31
  int layer = bid >> 4, g = bid & 15;
  int tid = threadIdx.x;       // 0..511
  int row = tid >> 5, o = tid & 31;
  const short* src = layer ? (ring + ((size_t)1 * NG + g) * 4096)
                           : (ys + ((size_t)2047 * NG + g) * 4096);
  float acc = 0.f;
#pragma unroll 8
  for (int h = 0; h < HH; ++h) {
    int f = h >> 5, lane = row + ((h & 31) >> 3) * 16, idx = h & 7;
    acc += bf2f(src[(size_t)f * 512 + lane * 8 + idx]) * Wout[o * HH + h];
  }
  out[((size_t)(layer * BB) + g * 16 + row) * 32 + o] = tanh_(acc + bout[o]);
}

extern "C" void kernel_launch(void* const* d_in, const int* in_sizes, int n_in,
                              void* d_out, int out_size, void* d_ws, size_t ws_size,
                              hipStream_t stream) {
  const float* x    = (const float*)d_in[0];
  const float* Wih0 = (const float*)d_in[1];
  const float* Whh0 = (const float*)d_in[2];
  const float* bih0 = (const float*)d_in[3];
  const float* bhh0 = (const float*)d_in[4];
  const float* Wih1 = (const float*)d_in[5];
  const float* Whh1 = (const float*)d_in[6];
  const float* bih1 = (const float*)d_in[7];
  const float* bhh1 = (const float*)d_in[8];
  const float* Wout = (const float*)d_in[9];
  const float* bout = (const float*)d_in[10];
  uint8_t* ws = (uint8_t*)d_ws;

  if (ws_size < WS_NEED) return;  // need ~269 MB of scratch

  hipMemsetAsync(ws, 0, 4096, stream);  // counters
  gru_rec<<<dim3(512), dim3(64), 0, stream>>>(x, Wih0, Whh0, bih0, bhh0,
                                              Wih1, Whh1, bih1, bhh1, ws);
  gru_out<<<dim3(32), dim3(512), 0, stream>>>(ws, Wout, bout, (float*)d_out);
}

// Round 2
// 5204.350 us; speedup vs baseline: 4.8973x; 4.8973x over previous
//
#include <hip/hip_runtime.h>
#include <stdint.h>

#define HH 256
#define SS 2048
#define BB 256
#define DD 64
#define NG 16   // batch groups (16 rows each)

typedef __attribute__((ext_vector_type(8))) short bh8;
typedef __attribute__((ext_vector_type(4))) float fx4;
typedef __attribute__((ext_vector_type(4))) float f4v;

__device__ __forceinline__ short f2bf(float f) {
  uint32_t u = __builtin_bit_cast(uint32_t, f);
  u += 0x7FFFu + ((u >> 16) & 1u);
  return (short)(u >> 16);
}
__device__ __forceinline__ float bf2f(short s) {
  uint32_t u = ((uint32_t)(uint16_t)s) << 16;
  return __builtin_bit_cast(float, u);
}
__device__ __forceinline__ float sigm_(float x) {
  x = fminf(fmaxf(x, -30.f), 30.f);
  return 1.0f / (1.0f + __expf(-x));
}
__device__ __forceinline__ float tanh_(float x) {
  x = fminf(fmaxf(x, -15.f), 15.f);
  float e = __expf(2.0f * x);
  return (e - 1.0f) / (e + 1.0f);
}
__device__ __forceinline__ fx4 mfma16(bh8 a, bh8 b, fx4 c) {
  return __builtin_amdgcn_mfma_f32_16x16x32_bf16(a, b, c, 0, 0, 0);
}
__device__ __forceinline__ bh8 cvt8(f4v a, f4v b) {
  bh8 r;
  r[0]=f2bf(a[0]); r[1]=f2bf(a[1]); r[2]=f2bf(a[2]); r[3]=f2bf(a[3]);
  r[4]=f2bf(b[0]); r[5]=f2bf(b[1]); r[6]=f2bf(b[2]); r[7]=f2bf(b[3]);
  return r;
}

// --- coherence-point (MALL) data path: no buffer_inv / buffer_wbl2 ---
__device__ __forceinline__ bh8 gload_cc(const short* p) {
  bh8 r;
  asm volatile("global_load_dwordx4 %0, %1, off sc0 sc1" : "=v"(r) : "v"(p));
  return r;
}
__device__ __forceinline__ void gstore_cc(short* p, int2 v) {
  asm volatile("global_store_dwordx2 %0, %1, off sc0 sc1" :: "v"(p), "v"(v) : "memory");
}
__device__ __forceinline__ void vwait0() {
  asm volatile("s_waitcnt vmcnt(0)" ::: "memory");
  __builtin_amdgcn_sched_barrier(0);   // rule #18: keep MFMAs behind the wait
}
__device__ __forceinline__ void wait_ge(uint32_t* c, uint32_t need, int l) {
  if (l == 0) {
    uint32_t s;
    do {
      s = __hip_atomic_load(c, __ATOMIC_RELAXED, __HIP_MEMORY_SCOPE_AGENT);
    } while (s < need);
  }
  __builtin_amdgcn_sched_barrier(0);
}

// ws layout (bytes):
//   [g*64]           : cnt0[g]  (one 64B line per group)
//   [2048 + g*64]    : cnt1[g]
//   [8192 ...]       : ys frags  [S][NG][8 frag][64 lane][8] bf16  = 256 MB
//   [8192 + 2^28 ..] : ring frags [2][NG][8][64][8] bf16           = 256 KB
#define YS_OFF   8192
#define RING_OFF (8192 + 268435456ull)
#define WS_NEED  (RING_OFF + 262144ull)

__global__ __launch_bounds__(64, 1) void gru_rec(
    const float* __restrict__ x,
    const float* __restrict__ Wih0, const float* __restrict__ Whh0,
    const float* __restrict__ bih0, const float* __restrict__ bhh0,
    const float* __restrict__ Wih1, const float* __restrict__ Whh1,
    const float* __restrict__ bih1, const float* __restrict__ bhh1,
    uint8_t* __restrict__ ws)
{
  const int l      = threadIdx.x;   // 0..63
  const int lane15 = l & 15;
  const int lgrp   = l >> 4;        // 0..3
  const int bid    = blockIdx.x;
  const int layer  = bid >> 8;
  const int r8     = bid & 255;
  const int g      = r8 & 15;       // group (batch tile)
  const int cp     = r8 >> 4;       // col wave 0..15
  const int jg     = cp * 16 + lane15;  // global h column
  const int fidx   = cp >> 1;       // frag index 0..7
  const int half   = cp & 1;        // frag half

  uint32_t* cnt0 = (uint32_t*)(ws + (size_t)g * 64);
  uint32_t* cnt1 = (uint32_t*)(ws + 2048 + (size_t)g * 64);
  short* ys   = (short*)(ws + YS_OFF);
  short* ring = (short*)(ws + RING_OFF);

  __shared__ short pub[256];  // 512B wave-local transpose buffer

  const float* Wih = layer ? Wih1 : Wih0;
  const float* Whh = layer ? Whh1 : Whh0;
  const float* bih = layer ? bih1 : bih0;
  const float* bhh = layer ? bhh1 : bhh0;

  const float biR = bih[jg],      biZ = bih[HH + jg],  biN = bih[2*HH + jg];
  const float bhR = bhh[jg],      bhZ = bhh[HH + jg],  bhN = bhh[2*HH + jg];

  // ---- W_hh B-fragments into registers (3 gates x 8 kfrags)
  bh8 whhF[3][8];
#pragma unroll
  for (int gi = 0; gi < 3; ++gi) {
    int grow = gi * HH + jg;
#pragma unroll
    for (int kf = 0; kf < 8; ++kf) {
      const float* p = Whh + (size_t)grow * HH + kf * 32 + lgrp * 8;
      whhF[gi][kf] = cvt8(*(const f4v*)p, *(const f4v*)(p + 4));
    }
  }

  float hp[4] = {0.f, 0.f, 0.f, 0.f};

  if (layer == 0) {
    // ---- W_ih0 frags (K=64 -> 2 kfrags)
    bh8 wihF[3][2];
#pragma unroll
    for (int gi = 0; gi < 3; ++gi) {
      int grow = gi * HH + jg;
#pragma unroll
      for (int kf = 0; kf < 2; ++kf) {
        const float* p = Wih + (size_t)grow * DD + kf * 32 + lgrp * 8;
        wihF[gi][kf] = cvt8(*(const f4v*)p, *(const f4v*)(p + 4));
      }
    }
    // preload x[0]
    const float* xp0 = x + ((size_t)0 * BB + g * 16 + lane15) * DD + lgrp * 8;
    f4v px0 = *(const f4v*)xp0,        px1 = *(const f4v*)(xp0 + 4);
    f4v px2 = *(const f4v*)(xp0 + 32), px3 = *(const f4v*)(xp0 + 36);

    for (int t = 0; t < SS; ++t) {
      // issue next-x prefetch first: the poll's drain completes it for free
      f4v nx0, nx1, nx2, nx3;
      if (t + 1 < SS) {
        const float* xp = x + ((size_t)(t+1) * BB + g * 16 + lane15) * DD + lgrp * 8;
        nx0 = *(const f4v*)xp;        nx1 = *(const f4v*)(xp + 4);
        nx2 = *(const f4v*)(xp + 32); nx3 = *(const f4v*)(xp + 36);
      }
      bh8 af[8];
      if (t > 0) {
        wait_ge(cnt0, 16u * (uint32_t)t, l);
        const short* asrc = ys + ((size_t)(t - 1) * NG + g) * 4096;
#pragma unroll
        for (int kf = 0; kf < 8; ++kf) af[kf] = gload_cc(asrc + kf * 512 + l * 8);
      }
      fx4 accR = {0,0,0,0}, accZ = {0,0,0,0}, accXN = {0,0,0,0}, accHN = {0,0,0,0};
      bh8 xf0 = cvt8(px0, px1), xf1 = cvt8(px2, px3);
      accR  = mfma16(xf0, wihF[0][0], accR);  accR  = mfma16(xf1, wihF[0][1], accR);
      accZ  = mfma16(xf0, wihF[1][0], accZ);  accZ  = mfma16(xf1, wihF[1][1], accZ);
      accXN = mfma16(xf0, wihF[2][0], accXN); accXN = mfma16(xf1, wihF[2][1], accXN);
      vwait0();   // af (and nx) complete
      if (t > 0) {
#pragma unroll
        for (int kf = 0; kf < 8; ++kf) {
          accR  = mfma16(af[kf], whhF[0][kf], accR);
          accZ  = mfma16(af[kf], whhF[1][kf], accZ);
          accHN = mfma16(af[kf], whhF[2][kf], accHN);
        }
      }
      px0 = nx0; px1 = nx1; px2 = nx2; px3 = nx3;
#pragma unroll
      for (int i = 0; i < 4; ++i) {
        float r = sigm_(accR[i] + biR + bhR);
        float z = sigm_(accZ[i] + biZ + bhZ);
        float n = tanh_(accXN[i] + biN + r * (accHN[i] + bhN));
        float h = (1.0f - z) * n + z * hp[i];
        short hb = f2bf(h);
        hp[i] = bf2f(hb);
        pub[(lgrp * 4 + i + ((lane15 >> 3) << 4)) * 8 + (lane15 & 7)] = hb;
      }
      __syncthreads();
      int2 v = *(const int2*)&pub[l * 4];
      short* dst = ys + (((size_t)t * NG + g) * 8 + fidx) * 512 + half * 256 + l * 4;
      gstore_cc(dst, v);
      asm volatile("s_waitcnt vmcnt(0)" ::: "memory");   // manual release
      if (l == 0)
        __hip_atomic_fetch_add(cnt0, 1u, __ATOMIC_RELAXED, __HIP_MEMORY_SCOPE_AGENT);
      __syncthreads();
    }
  } else {
    // ---- layer 1: W_ih1 frags (K=256 -> 8 kfrags)
    bh8 wihF[3][8];
#pragma unroll
    for (int gi = 0; gi < 3; ++gi) {
      int grow = gi * HH + jg;
#pragma unroll
      for (int kf = 0; kf < 8; ++kf) {
        const float* p = Wih + (size_t)grow * HH + kf * 32 + lgrp * 8;
        wihF[gi][kf] = cvt8(*(const f4v*)p, *(const f4v*)(p + 4));
      }
    }
    for (int t = 0; t < SS; ++t) {
      wait_ge(cnt0, 16u * (uint32_t)(t + 1), l);
      const short* xsrc = ys + ((size_t)t * NG + g) * 4096;
      bh8 xf[8];
#pragma unroll
      for (int kf = 0; kf < 8; ++kf) xf[kf] = gload_cc(xsrc + kf * 512 + l * 8);
      bh8 af[8];
      if (t > 0) {
        wait_ge(cnt1, 16u * (uint32_t)t, l);   // poll drains xf in parallel
        const short* asrc = ring + ((size_t)((t - 1) & 1) * NG + g) * 4096;
#pragma unroll
        for (int kf = 0; kf < 8; ++kf) af[kf] = gload_cc(asrc + kf * 512 + l * 8);
      }
      vwait0();
      fx4 accR = {0,0,0,0}, accZ = {0,0,0,0}, accXN = {0,0,0,0}, accHN = {0,0,0,0};
#pragma unroll
      for (int kf = 0; kf < 8; ++kf) {
        accR  = mfma16(xf[kf], wihF[0][kf], accR);
        accZ  = mfma16(xf[kf], wihF[1][kf], accZ);
        accXN = mfma16(xf[kf], wihF[2][kf], accXN);
      }
      if (t > 0) {
#pragma unroll
        for (int kf = 0; kf < 8; ++kf) {
          accR  = mfma16(af[kf], whhF[0][kf], accR);
          accZ  = mfma16(af[kf], whhF[1][kf], accZ);
          accHN = mfma16(af[kf], whhF[2][kf], accHN);
        }
      }
#pragma unroll
      for (int i = 0; i < 4; ++i) {
        float r = sigm_(accR[i] + biR + bhR);
        float z = sigm_(accZ[i] + biZ + bhZ);
        float n = tanh_(accXN[i] + biN + r * (accHN[i] + bhN));
        float h = (1.0f - z) * n + z * hp[i];
        short hb = f2bf(h);
        hp[i] = bf2f(hb);
        pub[(lgrp * 4 + i + ((lane15 >> 3) << 4)) * 8 + (lane15 & 7)] = hb;
      }
      __syncthreads();
      int2 v = *(const int2*)&pub[l * 4];
      short* dst = ring + (((size_t)(t & 1) * NG + g) * 8 + fidx) * 512 + half * 256 + l * 4;
      gstore_cc(dst, v);
      asm volatile("s_waitcnt vmcnt(0)" ::: "memory");   // manual release
      if (l == 0)
        __hip_atomic_fetch_add(cnt1, 1u, __ATOMIC_RELAXED, __HIP_MEMORY_SCOPE_AGENT);
      __syncthreads();
    }
  }
}

__global__ __launch_bounds__(512) void gru_out(
    const uint8_t* __restrict__ ws,
    const float* __restrict__ Wout, const float* __restrict__ bout,
    float* __restrict__ out)
{
  const short* ys   = (const short*)(ws + YS_OFF);
  const short* ring = (const short*)(ws + RING_OFF);
  int bid = blockIdx.x;        // 0..31
  int layer = bid >> 4, g = bid & 15;
  int tid = threadIdx.x;       // 0..511
  int row = tid >> 5, o = tid & 31;
  const short* src = layer ? (ring + ((size_t)1 * NG + g) * 4096)
                           : (ys + ((size_t)2047 * NG + g) * 4096);
  float acc = 0.f;
#pragma unroll 8
  for (int h = 0; h < HH; ++h) {
    int f = h >> 5, lane = row + ((h & 31) >> 3) * 16, idx = h & 7;
    acc += bf2f(src[(size_t)f * 512 + lane * 8 + idx]) * Wout[o * HH + h];
  }
  out[((size_t)(layer * BB) + g * 16 + row) * 32 + o] = tanh_(acc + bout[o]);
}

extern "C" void kernel_launch(void* const* d_in, const int* in_sizes, int n_in,
                              void* d_out, int out_size, void* d_ws, size_t ws_size,
                              hipStream_t stream) {
  const float* x    = (const float*)d_in[0];
  const float* Wih0 = (const float*)d_in[1];
  const float* Whh0 = (const float*)d_in[2];
  const float* bih0 = (const float*)d_in[3];
  const float* bhh0 = (const float*)d_in[4];
  const float* Wih1 = (const float*)d_in[5];
  const float* Whh1 = (const float*)d_in[6];
  const float* bih1 = (const float*)d_in[7];
  const float* bhh1 = (const float*)d_in[8];
  const float* Wout = (const float*)d_in[9];
  const float* bout = (const float*)d_in[10];
  uint8_t* ws = (uint8_t*)d_ws;

  if (ws_size < WS_NEED) return;  // need ~269 MB of scratch

  hipMemsetAsync(ws, 0, 4096, stream);  // counters
  gru_rec<<<dim3(512), dim3(64), 0, stream>>>(x, Wih0, Whh0, bih0, bhh0,
                                              Wih1, Whh1, bih1, bhh1, ws);
  gru_out<<<dim3(32), dim3(512), 0, stream>>>(ws, Wout, bout, (float*)d_out);
}